// Round 1
// baseline (1792.667 us; speedup 1.0000x reference)
//
#include <hip/hip_runtime.h>
#include <hip/hip_bf16.h>
#include <stdint.h>

// WeightOnlyInt8Linear: C[M,N] = A[M,K] @ dequant(W)[N,K]^T
//   A: fp32 [4096, 4096]  (input, flattened [2,2048,4096])
//   W: int32 [11008, 4096] (int8-valued)
//   S: fp32 [11008, 32]    (groupwise scales, group=128 along K)
//   C: fp32 [4096, 11008]
//
// Strategy: bf16 MFMA GEMM (16x16x32), scale folded into weight at LDS
// staging (bf16(w*s) — int8 exact in bf16, only the scale-fold rounds).
// BK=64 < GROUPSIZE=128 so each K-tile has a single group index.

typedef __bf16 bf16_t;
typedef bf16_t bf16x8 __attribute__((ext_vector_type(8)));
typedef float floatx4 __attribute__((ext_vector_type(4)));

#define M_TOT 4096
#define K_TOT 4096
#define N_TOT 11008
#define NGROUPS 32

#define BM 128
#define BN 128
#define BK 64

__global__ __launch_bounds__(256, 3)
void wq8_gemm_kernel(const float* __restrict__ A,
                     const int*   __restrict__ W,
                     const float* __restrict__ S,
                     float* __restrict__ C)
{
    // LDS tiles, chunk-XOR swizzled: element (r, c) lives at
    //   r*64 + ((c>>3) ^ (r&7))*8 + (c&7)
    // -> fragment ds_read_b128 is 16B aligned, rows 0..7 cover all 32 banks
    //    (2-way alias across 16 rows = free).
    __shared__ bf16_t As[BM * BK];
    __shared__ bf16_t Bs[BN * BK];

    const int tid = threadIdx.x;
    const int n0 = blockIdx.x * BN;
    const int m0 = blockIdx.y * BM;

    const int wave = tid >> 6;
    const int lane = tid & 63;
    const int wm = (wave >> 1) * 64;   // wave's m offset in tile
    const int wn = (wave & 1) * 64;    // wave's n offset in tile
    const int l15 = lane & 15;
    const int l4  = lane >> 4;         // quad 0..3

    floatx4 acc[4][4];
#pragma unroll
    for (int i = 0; i < 4; ++i)
#pragma unroll
        for (int j = 0; j < 4; ++j)
            acc[i][j] = (floatx4)0.0f;

    // staging map: 128x64 elems = 8192; 256 thr * 8 iters * float4
    const int srow = tid >> 4;         // 0..15 (+16*it)
    const int scol = (tid & 15) * 4;   // 0,4,...,60
    const int schunk = scol >> 3;
    const int soff = scol & 7;

    for (int k0 = 0; k0 < K_TOT; k0 += BK) {
        const int g = k0 >> 7;  // group index (BK=64 -> uniform per tile)

        // ---- stage A (fp32 -> bf16) ----
#pragma unroll
        for (int it = 0; it < 8; ++it) {
            const int r = it * 16 + srow;
            const float4 v = *(const float4*)(A + (size_t)(m0 + r) * K_TOT + k0 + scol);
            bf16_t* dst = &As[r * 64 + ((schunk ^ (r & 7)) << 3) + soff];
            dst[0] = (bf16_t)v.x;
            dst[1] = (bf16_t)v.y;
            dst[2] = (bf16_t)v.z;
            dst[3] = (bf16_t)v.w;
        }
        // ---- stage B (int32 * scale -> bf16) ----
#pragma unroll
        for (int it = 0; it < 8; ++it) {
            const int r = it * 16 + srow;
            const int4 wv = *(const int4*)(W + (size_t)(n0 + r) * K_TOT + k0 + scol);
            const float sc = S[(size_t)(n0 + r) * NGROUPS + g];
            bf16_t* dst = &Bs[r * 64 + ((schunk ^ (r & 7)) << 3) + soff];
            dst[0] = (bf16_t)((float)wv.x * sc);
            dst[1] = (bf16_t)((float)wv.y * sc);
            dst[2] = (bf16_t)((float)wv.z * sc);
            dst[3] = (bf16_t)((float)wv.w * sc);
        }
        __syncthreads();

        // ---- compute: 2 K-steps of 32 ----
#pragma unroll
        for (int ks = 0; ks < 2; ++ks) {
            bf16x8 af[4], bfr[4];
#pragma unroll
            for (int i = 0; i < 4; ++i) {
                const int m = wm + i * 16 + l15;
                const int kc = (l4 + ks * 4) ^ (m & 7);
                af[i] = *(const bf16x8*)&As[m * 64 + (kc << 3)];
                const int n = wn + i * 16 + l15;
                const int nkc = (l4 + ks * 4) ^ (n & 7);
                bfr[i] = *(const bf16x8*)&Bs[n * 64 + (nkc << 3)];
            }
#pragma unroll
            for (int i = 0; i < 4; ++i)
#pragma unroll
                for (int j = 0; j < 4; ++j)
                    acc[i][j] = __builtin_amdgcn_mfma_f32_16x16x32_bf16(
                        af[i], bfr[j], acc[i][j], 0, 0, 0);
        }
        __syncthreads();
    }

    // ---- epilogue: C/D layout col=lane&15, row=(lane>>4)*4+reg ----
#pragma unroll
    for (int i = 0; i < 4; ++i) {
        const int mb = m0 + wm + i * 16 + l4 * 4;
#pragma unroll
        for (int j = 0; j < 4; ++j) {
            const int n = n0 + wn + j * 16 + l15;
#pragma unroll
            for (int r = 0; r < 4; ++r)
                C[(size_t)(mb + r) * N_TOT + n] = acc[i][j][r];
        }
    }
}

extern "C" void kernel_launch(void* const* d_in, const int* in_sizes, int n_in,
                              void* d_out, int out_size, void* d_ws, size_t ws_size,
                              hipStream_t stream) {
    const float* A = (const float*)d_in[0];   // input  [2,2048,4096] fp32
    const int*   W = (const int*)d_in[1];     // weight [11008,4096] int32
    const float* S = (const float*)d_in[2];   // scales [11008,32] fp32
    float* C = (float*)d_out;                  // out    [2,2048,11008] fp32

    dim3 grid(N_TOT / BN, M_TOT / BM);  // (86, 32)
    dim3 block(256);
    wq8_gemm_kernel<<<grid, block, 0, stream>>>(A, W, S, C);
}

// Round 2
// 820.738 us; speedup vs baseline: 2.1842x; 2.1842x over previous
//
#include <hip/hip_runtime.h>
#include <hip/hip_bf16.h>
#include <stdint.h>

// WeightOnlyInt8Linear: C[M,N] = A[M,K] @ dequant(W)[N,K]^T
//   A: fp32 [4096, 4096], W: int32 [11008, 4096] (int8-valued),
//   S: fp32 [11008, 32] (group=128 along K), C: fp32 [4096, 11008]
//
// Round 2: hoist dtype conversion out of the K-loop.
//   pass 1: Wq = bf16(W * S) into ws   (90.2 MB)
//   pass 2: Aq = bf16(A) into ws       (33.6 MB)
//   pass 3: m97-structure GEMM: 128x128 tile, BK=64, global_load_lds w=16,
//           16x16x32 bf16 MFMA, 4x4 frags/wave, 2-barrier K-loop.

typedef __bf16 bf16_t;
typedef bf16_t bf16x8 __attribute__((ext_vector_type(8)));
typedef float floatx4 __attribute__((ext_vector_type(4)));

#define M_TOT 4096
#define K_TOT 4096
#define N_TOT 11008
#define NGROUPS 32

#define BM 128
#define BN 128
#define BK 64

// ---------------- pass 1: dequant weight to bf16 ----------------
// 45.09M elems, 8 per thread. k-chunk of 8 always within one group of 128.
__global__ __launch_bounds__(256)
void dequant_w_kernel(const int* __restrict__ W, const float* __restrict__ S,
                      bf16_t* __restrict__ Wq)
{
    const int t = blockIdx.x * 256 + threadIdx.x;
    const int c = t & 511;          // 512 chunks of 8 per row
    const int n = t >> 9;
    const size_t base = (size_t)n * K_TOT + c * 8;
    const int4 w0 = *(const int4*)(W + base);
    const int4 w1 = *(const int4*)(W + base + 4);
    const float sc = S[n * NGROUPS + (c >> 4)];   // (c*8)/128
    bf16x8 o;
    o[0] = (bf16_t)((float)w0.x * sc);
    o[1] = (bf16_t)((float)w0.y * sc);
    o[2] = (bf16_t)((float)w0.z * sc);
    o[3] = (bf16_t)((float)w0.w * sc);
    o[4] = (bf16_t)((float)w1.x * sc);
    o[5] = (bf16_t)((float)w1.y * sc);
    o[6] = (bf16_t)((float)w1.z * sc);
    o[7] = (bf16_t)((float)w1.w * sc);
    *(bf16x8*)(Wq + base) = o;
}

// ---------------- pass 2: A fp32 -> bf16 ----------------
__global__ __launch_bounds__(256)
void cvt_a_kernel(const float* __restrict__ A, bf16_t* __restrict__ Aq)
{
    const size_t base = ((size_t)blockIdx.x * 256 + threadIdx.x) * 8;
    const float4 a0 = *(const float4*)(A + base);
    const float4 a1 = *(const float4*)(A + base + 4);
    bf16x8 o;
    o[0] = (bf16_t)a0.x; o[1] = (bf16_t)a0.y; o[2] = (bf16_t)a0.z; o[3] = (bf16_t)a0.w;
    o[4] = (bf16_t)a1.x; o[5] = (bf16_t)a1.y; o[6] = (bf16_t)a1.z; o[7] = (bf16_t)a1.w;
    *(bf16x8*)(Aq + base) = o;
}

// ---------------- pass 3: bf16 MFMA GEMM (m97 structure) ----------------
__device__ __forceinline__ void gload_lds16(const bf16_t* g, bf16_t* lds)
{
    __builtin_amdgcn_global_load_lds(
        (const __attribute__((address_space(1))) unsigned int*)g,
        (__attribute__((address_space(3))) unsigned int*)lds,
        16, 0, 0);
}

__global__ __launch_bounds__(256, 3)
void wq8_gemm_bf16_kernel(const bf16_t* __restrict__ Aq,
                          const bf16_t* __restrict__ Wq,
                          float* __restrict__ C)
{
    // Row-major LDS tiles [128][64] bf16, NO padding (global_load_lds is
    // wave-uniform base + lane*16: lane l -> row l>>3, cols (l&7)*8).
    __shared__ bf16_t As[BM * BK];
    __shared__ bf16_t Bs[BN * BK];

    const int tid = threadIdx.x;
    const int n0 = blockIdx.x * BN;
    const int m0 = blockIdx.y * BM;

    const int wave = tid >> 6;
    const int lane = tid & 63;
    const int wm = (wave >> 1) * 64;
    const int wn = (wave & 1) * 64;
    const int l15 = lane & 15;
    const int l4  = lane >> 4;

    // staging: wave w stages rows w*32 .. w*32+31 of both tiles,
    // 4 global_load_lds (8 rows = 1KB each) per tile per wave.
    const int wrow = wave * 32;
    const int lrow = lane >> 3;          // 0..7
    const int lcol = (lane & 7) * 8;     // 0..56

    floatx4 acc[4][4];
#pragma unroll
    for (int i = 0; i < 4; ++i)
#pragma unroll
        for (int j = 0; j < 4; ++j)
            acc[i][j] = (floatx4)0.0f;

    const bf16_t* agp = Aq + (size_t)(m0 + wrow + lrow) * K_TOT + lcol;
    const bf16_t* bgp = Wq + (size_t)(n0 + wrow + lrow) * K_TOT + lcol;

    for (int k0 = 0; k0 < K_TOT; k0 += BK) {
#pragma unroll
        for (int ii = 0; ii < 4; ++ii) {
            gload_lds16(agp + (size_t)(ii * 8) * K_TOT + k0, &As[(wrow + ii * 8) * BK]);
            gload_lds16(bgp + (size_t)(ii * 8) * K_TOT + k0, &Bs[(wrow + ii * 8) * BK]);
        }
        __syncthreads();   // drains vmcnt(0): loads visible in LDS

#pragma unroll
        for (int ks = 0; ks < 2; ++ks) {
            bf16x8 af[4], bfr[4];
#pragma unroll
            for (int i = 0; i < 4; ++i) {
                af[i]  = *(const bf16x8*)&As[(wm + i * 16 + l15) * BK + ks * 32 + l4 * 8];
                bfr[i] = *(const bf16x8*)&Bs[(wn + i * 16 + l15) * BK + ks * 32 + l4 * 8];
            }
#pragma unroll
            for (int i = 0; i < 4; ++i)
#pragma unroll
                for (int j = 0; j < 4; ++j)
                    acc[i][j] = __builtin_amdgcn_mfma_f32_16x16x32_bf16(
                        af[i], bfr[j], acc[i][j], 0, 0, 0);
        }
        __syncthreads();   // protect LDS from next iteration's staging
    }

    // epilogue: C/D layout col=lane&15, row=(lane>>4)*4+reg
#pragma unroll
    for (int i = 0; i < 4; ++i) {
        const int mb = m0 + wm + i * 16 + l4 * 4;
#pragma unroll
        for (int j = 0; j < 4; ++j) {
            const int n = n0 + wn + j * 16 + l15;
#pragma unroll
            for (int r = 0; r < 4; ++r)
                C[(size_t)(mb + r) * N_TOT + n] = acc[i][j][r];
        }
    }
}

// ---------------- fallback (round-1 fused kernel, if ws too small) --------
__global__ __launch_bounds__(256, 3)
void wq8_gemm_fused_kernel(const float* __restrict__ A,
                           const int*   __restrict__ W,
                           const float* __restrict__ S,
                           float* __restrict__ C)
{
    __shared__ bf16_t As[BM * BK];
    __shared__ bf16_t Bs[BN * BK];

    const int tid = threadIdx.x;
    const int n0 = blockIdx.x * BN;
    const int m0 = blockIdx.y * BM;
    const int wave = tid >> 6;
    const int lane = tid & 63;
    const int wm = (wave >> 1) * 64;
    const int wn = (wave & 1) * 64;
    const int l15 = lane & 15;
    const int l4  = lane >> 4;

    floatx4 acc[4][4];
#pragma unroll
    for (int i = 0; i < 4; ++i)
#pragma unroll
        for (int j = 0; j < 4; ++j)
            acc[i][j] = (floatx4)0.0f;

    const int srow = tid >> 4;
    const int scol = (tid & 15) * 4;
    const int schunk = scol >> 3;
    const int soff = scol & 7;

    for (int k0 = 0; k0 < K_TOT; k0 += BK) {
        const int g = k0 >> 7;
#pragma unroll
        for (int it = 0; it < 8; ++it) {
            const int r = it * 16 + srow;
            const float4 v = *(const float4*)(A + (size_t)(m0 + r) * K_TOT + k0 + scol);
            bf16_t* dst = &As[r * 64 + ((schunk ^ (r & 7)) << 3) + soff];
            dst[0] = (bf16_t)v.x; dst[1] = (bf16_t)v.y;
            dst[2] = (bf16_t)v.z; dst[3] = (bf16_t)v.w;
        }
#pragma unroll
        for (int it = 0; it < 8; ++it) {
            const int r = it * 16 + srow;
            const int4 wv = *(const int4*)(W + (size_t)(n0 + r) * K_TOT + k0 + scol);
            const float sc = S[(size_t)(n0 + r) * NGROUPS + g];
            bf16_t* dst = &Bs[r * 64 + ((schunk ^ (r & 7)) << 3) + soff];
            dst[0] = (bf16_t)((float)wv.x * sc); dst[1] = (bf16_t)((float)wv.y * sc);
            dst[2] = (bf16_t)((float)wv.z * sc); dst[3] = (bf16_t)((float)wv.w * sc);
        }
        __syncthreads();
#pragma unroll
        for (int ks = 0; ks < 2; ++ks) {
            bf16x8 af[4], bfr[4];
#pragma unroll
            for (int i = 0; i < 4; ++i) {
                const int m = wm + i * 16 + l15;
                const int kc = (l4 + ks * 4) ^ (m & 7);
                af[i] = *(const bf16x8*)&As[m * 64 + (kc << 3)];
                const int n = wn + i * 16 + l15;
                const int nkc = (l4 + ks * 4) ^ (n & 7);
                bfr[i] = *(const bf16x8*)&Bs[n * 64 + (nkc << 3)];
            }
#pragma unroll
            for (int i = 0; i < 4; ++i)
#pragma unroll
                for (int j = 0; j < 4; ++j)
                    acc[i][j] = __builtin_amdgcn_mfma_f32_16x16x32_bf16(
                        af[i], bfr[j], acc[i][j], 0, 0, 0);
        }
        __syncthreads();
    }
#pragma unroll
    for (int i = 0; i < 4; ++i) {
        const int mb = m0 + wm + i * 16 + l4 * 4;
#pragma unroll
        for (int j = 0; j < 4; ++j) {
            const int n = n0 + wn + j * 16 + l15;
#pragma unroll
            for (int r = 0; r < 4; ++r)
                C[(size_t)(mb + r) * N_TOT + n] = acc[i][j][r];
        }
    }
}

extern "C" void kernel_launch(void* const* d_in, const int* in_sizes, int n_in,
                              void* d_out, int out_size, void* d_ws, size_t ws_size,
                              hipStream_t stream) {
    const float* A = (const float*)d_in[0];
    const int*   W = (const int*)d_in[1];
    const float* S = (const float*)d_in[2];
    float* C = (float*)d_out;

    const size_t wq_bytes = (size_t)N_TOT * K_TOT * sizeof(bf16_t);  // 90.2 MB
    const size_t aq_bytes = (size_t)M_TOT * K_TOT * sizeof(bf16_t);  // 33.6 MB

    if (ws_size >= wq_bytes + aq_bytes) {
        bf16_t* Wq = (bf16_t*)d_ws;
        bf16_t* Aq = (bf16_t*)((char*)d_ws + wq_bytes);

        dequant_w_kernel<<<(N_TOT * (K_TOT / 8)) / 256, 256, 0, stream>>>(W, S, Wq);
        cvt_a_kernel<<<((size_t)M_TOT * (K_TOT / 8)) / 256, 256, 0, stream>>>(A, Aq);

        dim3 grid(N_TOT / BN, M_TOT / BM);  // (86, 32)
        wq8_gemm_bf16_kernel<<<grid, dim3(256), 0, stream>>>(Aq, Wq, C);
    } else {
        dim3 grid(N_TOT / BN, M_TOT / BM);
        wq8_gemm_fused_kernel<<<grid, dim3(256), 0, stream>>>(A, W, S, C);
    }
}

// Round 3
// 796.010 us; speedup vs baseline: 2.2521x; 1.0311x over previous
//
#include <hip/hip_runtime.h>
#include <hip/hip_bf16.h>
#include <stdint.h>

// WeightOnlyInt8Linear: C[M,N] = A[M,K] @ dequant(W)[N,K]^T
//   A: fp32 [4096, 4096], W: int32 [11008, 4096] (int8-valued),
//   S: fp32 [11008, 32] (group=128 along K), C: fp32 [4096, 11008]
//
// Round 3: round-2 structure + bank-conflict fix.
//   Pre-passes write ws with per-row XOR-swizzled 16B chunks
//   (chunk c of row r stored at position c^(r&7) within each 64-col block).
//   global_load_lds copies linearly -> LDS inherits the swizzle ->
//   fragment ds_read_b128 with matching XOR is conflict-free (2-way only).

typedef __bf16 bf16_t;
typedef bf16_t bf16x8 __attribute__((ext_vector_type(8)));
typedef float floatx4 __attribute__((ext_vector_type(4)));

#define M_TOT 4096
#define K_TOT 4096
#define N_TOT 11008
#define NGROUPS 32

#define BM 128
#define BN 128
#define BK 64

// ---------------- pass 1: dequant weight to bf16, swizzled ----------------
__global__ __launch_bounds__(256)
void dequant_w_kernel(const int* __restrict__ W, const float* __restrict__ S,
                      bf16_t* __restrict__ Wq)
{
    const int t = blockIdx.x * 256 + threadIdx.x;
    const int c = t & 511;          // chunk of 8 along K (512/row)
    const int n = t >> 9;
    const size_t ibase = (size_t)n * K_TOT + c * 8;
    const int4 w0 = *(const int4*)(W + ibase);
    const int4 w1 = *(const int4*)(W + ibase + 4);
    const float sc = S[n * NGROUPS + (c >> 4)];
    bf16x8 o;
    o[0] = (bf16_t)((float)w0.x * sc);
    o[1] = (bf16_t)((float)w0.y * sc);
    o[2] = (bf16_t)((float)w0.z * sc);
    o[3] = (bf16_t)((float)w0.w * sc);
    o[4] = (bf16_t)((float)w1.x * sc);
    o[5] = (bf16_t)((float)w1.y * sc);
    o[6] = (bf16_t)((float)w1.z * sc);
    o[7] = (bf16_t)((float)w1.w * sc);
    // swizzle: within each 64-col block, chunk c&7 -> (c&7)^(n&7)
    const int cc = (c & 7) ^ (n & 7);
    const size_t obase = (size_t)n * K_TOT + (size_t)(c >> 3) * 64 + cc * 8;
    *(bf16x8*)(Wq + obase) = o;
}

// ---------------- pass 2: A fp32 -> bf16, swizzled ----------------
__global__ __launch_bounds__(256)
void cvt_a_kernel(const float* __restrict__ A, bf16_t* __restrict__ Aq)
{
    const int t = blockIdx.x * 256 + threadIdx.x;
    const int c = t & 511;
    const int m = t >> 9;
    const size_t ibase = (size_t)m * K_TOT + c * 8;
    const float4 a0 = *(const float4*)(A + ibase);
    const float4 a1 = *(const float4*)(A + ibase + 4);
    bf16x8 o;
    o[0] = (bf16_t)a0.x; o[1] = (bf16_t)a0.y; o[2] = (bf16_t)a0.z; o[3] = (bf16_t)a0.w;
    o[4] = (bf16_t)a1.x; o[5] = (bf16_t)a1.y; o[6] = (bf16_t)a1.z; o[7] = (bf16_t)a1.w;
    const int cc = (c & 7) ^ (m & 7);
    const size_t obase = (size_t)m * K_TOT + (size_t)(c >> 3) * 64 + cc * 8;
    *(bf16x8*)(Aq + obase) = o;
}

// ---------------- pass 3: bf16 MFMA GEMM ----------------
__device__ __forceinline__ void gload_lds16(const bf16_t* g, bf16_t* lds)
{
    __builtin_amdgcn_global_load_lds(
        (const __attribute__((address_space(1))) unsigned int*)g,
        (__attribute__((address_space(3))) unsigned int*)lds,
        16, 0, 0);
}

__global__ __launch_bounds__(256, 3)
void wq8_gemm_bf16_kernel(const bf16_t* __restrict__ Aq,
                          const bf16_t* __restrict__ Wq,
                          float* __restrict__ C)
{
    // LDS rows are the swizzled ws rows (global_load_lds copies linearly).
    __shared__ bf16_t As[BM * BK];
    __shared__ bf16_t Bs[BN * BK];

    const int tid = threadIdx.x;
    const int n0 = blockIdx.x * BN;
    const int m0 = blockIdx.y * BM;

    const int wave = tid >> 6;
    const int lane = tid & 63;
    const int wm = (wave >> 1) * 64;
    const int wn = (wave & 1) * 64;
    const int l15 = lane & 15;
    const int l4  = lane >> 4;
    const int key = lane & 7;          // swizzle key = row&7 of fragment row

    const int wrow = wave * 32;
    const int lrow = lane >> 3;          // 0..7
    const int lcol = (lane & 7) * 8;     // 0..56

    floatx4 acc[4][4];
#pragma unroll
    for (int i = 0; i < 4; ++i)
#pragma unroll
        for (int j = 0; j < 4; ++j)
            acc[i][j] = (floatx4)0.0f;

    const bf16_t* agp = Aq + (size_t)(m0 + wrow + lrow) * K_TOT + lcol;
    const bf16_t* bgp = Wq + (size_t)(n0 + wrow + lrow) * K_TOT + lcol;

    for (int k0 = 0; k0 < K_TOT; k0 += BK) {
#pragma unroll
        for (int ii = 0; ii < 4; ++ii) {
            gload_lds16(agp + (size_t)(ii * 8) * K_TOT + k0, &As[(wrow + ii * 8) * BK]);
            gload_lds16(bgp + (size_t)(ii * 8) * K_TOT + k0, &Bs[(wrow + ii * 8) * BK]);
        }
        __syncthreads();

#pragma unroll
        for (int ks = 0; ks < 2; ++ks) {
            bf16x8 af[4], bfr[4];
            const int chunk = (ks * 4 + l4) ^ key;   // XOR-swizzled chunk
#pragma unroll
            for (int i = 0; i < 4; ++i) {
                af[i]  = *(const bf16x8*)&As[(wm + i * 16 + l15) * BK + chunk * 8];
                bfr[i] = *(const bf16x8*)&Bs[(wn + i * 16 + l15) * BK + chunk * 8];
            }
#pragma unroll
            for (int i = 0; i < 4; ++i)
#pragma unroll
                for (int j = 0; j < 4; ++j)
                    acc[i][j] = __builtin_amdgcn_mfma_f32_16x16x32_bf16(
                        af[i], bfr[j], acc[i][j], 0, 0, 0);
        }
        __syncthreads();
    }

    // epilogue: C/D layout col=lane&15, row=(lane>>4)*4+reg
#pragma unroll
    for (int i = 0; i < 4; ++i) {
        const int mb = m0 + wm + i * 16 + l4 * 4;
#pragma unroll
        for (int j = 0; j < 4; ++j) {
            const int n = n0 + wn + j * 16 + l15;
#pragma unroll
            for (int r = 0; r < 4; ++r)
                C[(size_t)(mb + r) * N_TOT + n] = acc[i][j][r];
        }
    }
}

// ---------------- fallback (fully fused, if ws too small) --------
__global__ __launch_bounds__(256, 3)
void wq8_gemm_fused_kernel(const float* __restrict__ A,
                           const int*   __restrict__ W,
                           const float* __restrict__ S,
                           float* __restrict__ C)
{
    __shared__ bf16_t As[BM * BK];
    __shared__ bf16_t Bs[BN * BK];

    const int tid = threadIdx.x;
    const int n0 = blockIdx.x * BN;
    const int m0 = blockIdx.y * BM;
    const int wave = tid >> 6;
    const int lane = tid & 63;
    const int wm = (wave >> 1) * 64;
    const int wn = (wave & 1) * 64;
    const int l15 = lane & 15;
    const int l4  = lane >> 4;

    floatx4 acc[4][4];
#pragma unroll
    for (int i = 0; i < 4; ++i)
#pragma unroll
        for (int j = 0; j < 4; ++j)
            acc[i][j] = (floatx4)0.0f;

    const int srow = tid >> 4;
    const int scol = (tid & 15) * 4;
    const int schunk = scol >> 3;
    const int soff = scol & 7;

    for (int k0 = 0; k0 < K_TOT; k0 += BK) {
        const int g = k0 >> 7;
#pragma unroll
        for (int it = 0; it < 8; ++it) {
            const int r = it * 16 + srow;
            const float4 v = *(const float4*)(A + (size_t)(m0 + r) * K_TOT + k0 + scol);
            bf16_t* dst = &As[r * 64 + ((schunk ^ (r & 7)) << 3) + soff];
            dst[0] = (bf16_t)v.x; dst[1] = (bf16_t)v.y;
            dst[2] = (bf16_t)v.z; dst[3] = (bf16_t)v.w;
        }
#pragma unroll
        for (int it = 0; it < 8; ++it) {
            const int r = it * 16 + srow;
            const int4 wv = *(const int4*)(W + (size_t)(n0 + r) * K_TOT + k0 + scol);
            const float sc = S[(size_t)(n0 + r) * NGROUPS + g];
            bf16_t* dst = &Bs[r * 64 + ((schunk ^ (r & 7)) << 3) + soff];
            dst[0] = (bf16_t)((float)wv.x * sc); dst[1] = (bf16_t)((float)wv.y * sc);
            dst[2] = (bf16_t)((float)wv.z * sc); dst[3] = (bf16_t)((float)wv.w * sc);
        }
        __syncthreads();
#pragma unroll
        for (int ks = 0; ks < 2; ++ks) {
            bf16x8 af[4], bfr[4];
#pragma unroll
            for (int i = 0; i < 4; ++i) {
                const int m = wm + i * 16 + l15;
                const int kc = (l4 + ks * 4) ^ (m & 7);
                af[i] = *(const bf16x8*)&As[m * 64 + (kc << 3)];
                const int n = wn + i * 16 + l15;
                const int nkc = (l4 + ks * 4) ^ (n & 7);
                bfr[i] = *(const bf16x8*)&Bs[n * 64 + (nkc << 3)];
            }
#pragma unroll
            for (int i = 0; i < 4; ++i)
#pragma unroll
                for (int j = 0; j < 4; ++j)
                    acc[i][j] = __builtin_amdgcn_mfma_f32_16x16x32_bf16(
                        af[i], bfr[j], acc[i][j], 0, 0, 0);
        }
        __syncthreads();
    }
#pragma unroll
    for (int i = 0; i < 4; ++i) {
        const int mb = m0 + wm + i * 16 + l4 * 4;
#pragma unroll
        for (int j = 0; j < 4; ++j) {
            const int n = n0 + wn + j * 16 + l15;
#pragma unroll
            for (int r = 0; r < 4; ++r)
                C[(size_t)(mb + r) * N_TOT + n] = acc[i][j][r];
        }
    }
}

extern "C" void kernel_launch(void* const* d_in, const int* in_sizes, int n_in,
                              void* d_out, int out_size, void* d_ws, size_t ws_size,
                              hipStream_t stream) {
    const float* A = (const float*)d_in[0];
    const int*   W = (const int*)d_in[1];
    const float* S = (const float*)d_in[2];
    float* C = (float*)d_out;

    const size_t wq_bytes = (size_t)N_TOT * K_TOT * sizeof(bf16_t);  // 90.2 MB
    const size_t aq_bytes = (size_t)M_TOT * K_TOT * sizeof(bf16_t);  // 33.6 MB

    if (ws_size >= wq_bytes + aq_bytes) {
        bf16_t* Wq = (bf16_t*)d_ws;
        bf16_t* Aq = (bf16_t*)((char*)d_ws + wq_bytes);

        dequant_w_kernel<<<(N_TOT * (K_TOT / 8)) / 256, 256, 0, stream>>>(W, S, Wq);
        cvt_a_kernel<<<((size_t)M_TOT * (K_TOT / 8)) / 256, 256, 0, stream>>>(A, Aq);

        dim3 grid(N_TOT / BN, M_TOT / BM);  // (86, 32)
        wq8_gemm_bf16_kernel<<<grid, dim3(256), 0, stream>>>(Aq, Wq, C);
    } else {
        dim3 grid(N_TOT / BN, M_TOT / BM);
        wq8_gemm_fused_kernel<<<grid, dim3(256), 0, stream>>>(A, W, S, C);
    }
}

// Round 4
// 756.603 us; speedup vs baseline: 2.3694x; 1.0521x over previous
//
#include <hip/hip_runtime.h>
#include <hip/hip_bf16.h>
#include <stdint.h>

// WeightOnlyInt8Linear: C[M,N] = A[M,K] @ dequant(W)[N,K]^T
//   A: fp32 [4096, 4096], W: int32 [11008, 4096] (int8-valued),
//   S: fp32 [11008, 32] (group=128 along K), C: fp32 [4096, 11008]
//
// Round 4 = round 3 (ws-swizzled bf16 pre-dequant + global_load_lds GEMM,
// 0 bank conflicts) + two latency fixes:
//   1. supertile block swizzle (8 N-tiles x 32 M-tiles per supertile) so
//      concurrently-resident blocks reuse Wq/Aq in L3 (fetch 1.6GB -> ~0.55GB)
//   2. __launch_bounds__(256,4): squeeze VGPR+AGPR <= 128 -> 4 blocks/CU
//      (was 132 -> 3 blocks/CU).

typedef __bf16 bf16_t;
typedef bf16_t bf16x8 __attribute__((ext_vector_type(8)));
typedef float floatx4 __attribute__((ext_vector_type(4)));

#define M_TOT 4096
#define K_TOT 4096
#define N_TOT 11008
#define NGROUPS 32

#define BM 128
#define BN 128
#define BK 64

#define M_TILES 32
#define N_TILES 86
#define N_SUPER 8   // N-tiles per supertile

// ---------------- pass 1: dequant weight to bf16, swizzled ----------------
__global__ __launch_bounds__(256)
void dequant_w_kernel(const int* __restrict__ W, const float* __restrict__ S,
                      bf16_t* __restrict__ Wq)
{
    const int t = blockIdx.x * 256 + threadIdx.x;
    const int c = t & 511;          // chunk of 8 along K (512/row)
    const int n = t >> 9;
    const size_t ibase = (size_t)n * K_TOT + c * 8;
    const int4 w0 = *(const int4*)(W + ibase);
    const int4 w1 = *(const int4*)(W + ibase + 4);
    const float sc = S[n * NGROUPS + (c >> 4)];
    bf16x8 o;
    o[0] = (bf16_t)((float)w0.x * sc);
    o[1] = (bf16_t)((float)w0.y * sc);
    o[2] = (bf16_t)((float)w0.z * sc);
    o[3] = (bf16_t)((float)w0.w * sc);
    o[4] = (bf16_t)((float)w1.x * sc);
    o[5] = (bf16_t)((float)w1.y * sc);
    o[6] = (bf16_t)((float)w1.z * sc);
    o[7] = (bf16_t)((float)w1.w * sc);
    // swizzle: within each 64-col block, chunk c&7 -> (c&7)^(n&7)
    const int cc = (c & 7) ^ (n & 7);
    const size_t obase = (size_t)n * K_TOT + (size_t)(c >> 3) * 64 + cc * 8;
    *(bf16x8*)(Wq + obase) = o;
}

// ---------------- pass 2: A fp32 -> bf16, swizzled ----------------
__global__ __launch_bounds__(256)
void cvt_a_kernel(const float* __restrict__ A, bf16_t* __restrict__ Aq)
{
    const int t = blockIdx.x * 256 + threadIdx.x;
    const int c = t & 511;
    const int m = t >> 9;
    const size_t ibase = (size_t)m * K_TOT + c * 8;
    const float4 a0 = *(const float4*)(A + ibase);
    const float4 a1 = *(const float4*)(A + ibase + 4);
    bf16x8 o;
    o[0] = (bf16_t)a0.x; o[1] = (bf16_t)a0.y; o[2] = (bf16_t)a0.z; o[3] = (bf16_t)a0.w;
    o[4] = (bf16_t)a1.x; o[5] = (bf16_t)a1.y; o[6] = (bf16_t)a1.z; o[7] = (bf16_t)a1.w;
    const int cc = (c & 7) ^ (m & 7);
    const size_t obase = (size_t)m * K_TOT + (size_t)(c >> 3) * 64 + cc * 8;
    *(bf16x8*)(Aq + obase) = o;
}

// ---------------- pass 3: bf16 MFMA GEMM ----------------
__device__ __forceinline__ void gload_lds16(const bf16_t* g, bf16_t* lds)
{
    __builtin_amdgcn_global_load_lds(
        (const __attribute__((address_space(1))) unsigned int*)g,
        (__attribute__((address_space(3))) unsigned int*)lds,
        16, 0, 0);
}

__global__ __launch_bounds__(256, 4)
void wq8_gemm_bf16_kernel(const bf16_t* __restrict__ Aq,
                          const bf16_t* __restrict__ Wq,
                          float* __restrict__ C)
{
    __shared__ bf16_t As[BM * BK];
    __shared__ bf16_t Bs[BN * BK];

    // supertile swizzle: full supertile = 8 N-tiles x 32 M-tiles = 256 blocks,
    // remainder supertile = 6 N-tiles x 32 M-tiles = 192 blocks.
    const int bid = blockIdx.x;
    int mt, nt;
    if (bid < (N_TILES / N_SUPER) * N_SUPER * M_TILES) {   // < 2560
        const int g = bid >> 8;        // /256
        const int r = bid & 255;
        nt = g * N_SUPER + (r & 7);
        mt = r >> 3;
    } else {
        const int r = bid - (N_TILES / N_SUPER) * N_SUPER * M_TILES;  // 0..191
        nt = 80 + r % 6;
        mt = r / 6;
    }
    const int n0 = nt * BN;
    const int m0 = mt * BM;

    const int tid = threadIdx.x;
    const int wave = tid >> 6;
    const int lane = tid & 63;
    const int wm = (wave >> 1) * 64;
    const int wn = (wave & 1) * 64;
    const int l15 = lane & 15;
    const int l4  = lane >> 4;
    const int key = lane & 7;          // swizzle key

    const int wrow = wave * 32;
    const int lrow = lane >> 3;          // 0..7
    const int lcol = (lane & 7) * 8;     // 0..56

    floatx4 acc[4][4];
#pragma unroll
    for (int i = 0; i < 4; ++i)
#pragma unroll
        for (int j = 0; j < 4; ++j)
            acc[i][j] = (floatx4)0.0f;

    const bf16_t* agp = Aq + (size_t)(m0 + wrow + lrow) * K_TOT + lcol;
    const bf16_t* bgp = Wq + (size_t)(n0 + wrow + lrow) * K_TOT + lcol;

    for (int k0 = 0; k0 < K_TOT; k0 += BK) {
#pragma unroll
        for (int ii = 0; ii < 4; ++ii) {
            gload_lds16(agp + (size_t)(ii * 8) * K_TOT + k0, &As[(wrow + ii * 8) * BK]);
            gload_lds16(bgp + (size_t)(ii * 8) * K_TOT + k0, &Bs[(wrow + ii * 8) * BK]);
        }
        __syncthreads();

#pragma unroll
        for (int ks = 0; ks < 2; ++ks) {
            bf16x8 af[4], bfr[4];
            const int chunk = (ks * 4 + l4) ^ key;
#pragma unroll
            for (int i = 0; i < 4; ++i) {
                af[i]  = *(const bf16x8*)&As[(wm + i * 16 + l15) * BK + chunk * 8];
                bfr[i] = *(const bf16x8*)&Bs[(wn + i * 16 + l15) * BK + chunk * 8];
            }
#pragma unroll
            for (int i = 0; i < 4; ++i)
#pragma unroll
                for (int j = 0; j < 4; ++j)
                    acc[i][j] = __builtin_amdgcn_mfma_f32_16x16x32_bf16(
                        af[i], bfr[j], acc[i][j], 0, 0, 0);
        }
        __syncthreads();
    }

    // epilogue: C/D layout col=lane&15, row=(lane>>4)*4+reg
#pragma unroll
    for (int i = 0; i < 4; ++i) {
        const int mb = m0 + wm + i * 16 + l4 * 4;
#pragma unroll
        for (int j = 0; j < 4; ++j) {
            const int n = n0 + wn + j * 16 + l15;
#pragma unroll
            for (int r = 0; r < 4; ++r)
                C[(size_t)(mb + r) * N_TOT + n] = acc[i][j][r];
        }
    }
}

// ---------------- fallback (fully fused, if ws too small) --------
__global__ __launch_bounds__(256, 3)
void wq8_gemm_fused_kernel(const float* __restrict__ A,
                           const int*   __restrict__ W,
                           const float* __restrict__ S,
                           float* __restrict__ C)
{
    __shared__ bf16_t As[BM * BK];
    __shared__ bf16_t Bs[BN * BK];

    const int tid = threadIdx.x;
    const int n0 = blockIdx.x * BN;
    const int m0 = blockIdx.y * BM;
    const int wave = tid >> 6;
    const int lane = tid & 63;
    const int wm = (wave >> 1) * 64;
    const int wn = (wave & 1) * 64;
    const int l15 = lane & 15;
    const int l4  = lane >> 4;

    floatx4 acc[4][4];
#pragma unroll
    for (int i = 0; i < 4; ++i)
#pragma unroll
        for (int j = 0; j < 4; ++j)
            acc[i][j] = (floatx4)0.0f;

    const int srow = tid >> 4;
    const int scol = (tid & 15) * 4;
    const int schunk = scol >> 3;
    const int soff = scol & 7;

    for (int k0 = 0; k0 < K_TOT; k0 += BK) {
        const int g = k0 >> 7;
#pragma unroll
        for (int it = 0; it < 8; ++it) {
            const int r = it * 16 + srow;
            const float4 v = *(const float4*)(A + (size_t)(m0 + r) * K_TOT + k0 + scol);
            bf16_t* dst = &As[r * 64 + ((schunk ^ (r & 7)) << 3) + soff];
            dst[0] = (bf16_t)v.x; dst[1] = (bf16_t)v.y;
            dst[2] = (bf16_t)v.z; dst[3] = (bf16_t)v.w;
        }
#pragma unroll
        for (int it = 0; it < 8; ++it) {
            const int r = it * 16 + srow;
            const int4 wv = *(const int4*)(W + (size_t)(n0 + r) * K_TOT + k0 + scol);
            const float sc = S[(size_t)(n0 + r) * NGROUPS + g];
            bf16_t* dst = &Bs[r * 64 + ((schunk ^ (r & 7)) << 3) + soff];
            dst[0] = (bf16_t)((float)wv.x * sc); dst[1] = (bf16_t)((float)wv.y * sc);
            dst[2] = (bf16_t)((float)wv.z * sc); dst[3] = (bf16_t)((float)wv.w * sc);
        }
        __syncthreads();
#pragma unroll
        for (int ks = 0; ks < 2; ++ks) {
            bf16x8 af[4], bfr[4];
#pragma unroll
            for (int i = 0; i < 4; ++i) {
                const int m = wm + i * 16 + l15;
                const int kc = (l4 + ks * 4) ^ (m & 7);
                af[i] = *(const bf16x8*)&As[m * 64 + (kc << 3)];
                const int n = wn + i * 16 + l15;
                const int nkc = (l4 + ks * 4) ^ (n & 7);
                bfr[i] = *(const bf16x8*)&Bs[n * 64 + (nkc << 3)];
            }
#pragma unroll
            for (int i = 0; i < 4; ++i)
#pragma unroll
                for (int j = 0; j < 4; ++j)
                    acc[i][j] = __builtin_amdgcn_mfma_f32_16x16x32_bf16(
                        af[i], bfr[j], acc[i][j], 0, 0, 0);
        }
        __syncthreads();
    }
#pragma unroll
    for (int i = 0; i < 4; ++i) {
        const int mb = m0 + wm + i * 16 + l4 * 4;
#pragma unroll
        for (int j = 0; j < 4; ++j) {
            const int n = n0 + wn + j * 16 + l15;
#pragma unroll
            for (int r = 0; r < 4; ++r)
                C[(size_t)(mb + r) * N_TOT + n] = acc[i][j][r];
        }
    }
}

extern "C" void kernel_launch(void* const* d_in, const int* in_sizes, int n_in,
                              void* d_out, int out_size, void* d_ws, size_t ws_size,
                              hipStream_t stream) {
    const float* A = (const float*)d_in[0];
    const int*   W = (const int*)d_in[1];
    const float* S = (const float*)d_in[2];
    float* C = (float*)d_out;

    const size_t wq_bytes = (size_t)N_TOT * K_TOT * sizeof(bf16_t);  // 90.2 MB
    const size_t aq_bytes = (size_t)M_TOT * K_TOT * sizeof(bf16_t);  // 33.6 MB

    if (ws_size >= wq_bytes + aq_bytes) {
        bf16_t* Wq = (bf16_t*)d_ws;
        bf16_t* Aq = (bf16_t*)((char*)d_ws + wq_bytes);

        dequant_w_kernel<<<(N_TOT * (K_TOT / 8)) / 256, 256, 0, stream>>>(W, S, Wq);
        cvt_a_kernel<<<((size_t)M_TOT * (K_TOT / 8)) / 256, 256, 0, stream>>>(A, Aq);

        wq8_gemm_bf16_kernel<<<dim3(M_TILES * N_TILES), dim3(256), 0, stream>>>(Aq, Wq, C);
    } else {
        dim3 grid(N_TOT / BN, M_TOT / BM);
        wq8_gemm_fused_kernel<<<grid, dim3(256), 0, stream>>>(A, W, S, C);
    }
}